// Round 18
// baseline (211.295 us; speedup 1.0000x reference)
//
#include <hip/hip_runtime.h>
#include <hip/hip_bf16.h>

#define B_ 4
#define S_ 4096
#define E_ 1024
#define D_ 128

typedef unsigned short u16;
typedef __bf16 bf16x8 __attribute__((ext_vector_type(8)));
typedef unsigned short u16x8 __attribute__((ext_vector_type(8)));
typedef float f32x4 __attribute__((ext_vector_type(4)));

__device__ inline u16 f2bf(float f) {
    __bf16 h = (__bf16)f;
    return __builtin_bit_cast(u16, h);
}

// direct global->LDS DMA, 16B per lane, no VGPR round-trip
__device__ inline void gload16(const void* g, void* l) {
    __builtin_amdgcn_global_load_lds(
        (const __attribute__((address_space(1))) void*)g,
        (__attribute__((address_space(3))) void*)l, 16, 0, 0);
}

__device__ inline bf16x8 cvt8(float4 lo, float4 hi) {
    union { bf16x8 v; __bf16 e[8]; } a;
    a.e[0] = (__bf16)lo.x; a.e[1] = (__bf16)lo.y;
    a.e[2] = (__bf16)lo.z; a.e[3] = (__bf16)lo.w;
    a.e[4] = (__bf16)hi.x; a.e[5] = (__bf16)hi.y;
    a.e[6] = (__bf16)hi.z; a.e[7] = (__bf16)hi.w;
    return a.v;
}

// VALU-pipe (DPP) butterfly reductions over 16-lane rows.
__device__ inline float dpp_max16(float x) {
    int v = __builtin_bit_cast(int, x);
    x = fmaxf(x, __builtin_bit_cast(float, __builtin_amdgcn_update_dpp(0, v, 0xB1, 0xF, 0xF, true)));
    v = __builtin_bit_cast(int, x);
    x = fmaxf(x, __builtin_bit_cast(float, __builtin_amdgcn_update_dpp(0, v, 0x4E, 0xF, 0xF, true)));
    v = __builtin_bit_cast(int, x);
    x = fmaxf(x, __builtin_bit_cast(float, __builtin_amdgcn_update_dpp(0, v, 0x141, 0xF, 0xF, true)));
    v = __builtin_bit_cast(int, x);
    x = fmaxf(x, __builtin_bit_cast(float, __builtin_amdgcn_update_dpp(0, v, 0x140, 0xF, 0xF, true)));
    return x;
}
__device__ inline float dpp_add16(float x) {
    int v = __builtin_bit_cast(int, x);
    x += __builtin_bit_cast(float, __builtin_amdgcn_update_dpp(0, v, 0xB1, 0xF, 0xF, true));
    v = __builtin_bit_cast(int, x);
    x += __builtin_bit_cast(float, __builtin_amdgcn_update_dpp(0, v, 0x4E, 0xF, 0xF, true));
    v = __builtin_bit_cast(int, x);
    x += __builtin_bit_cast(float, __builtin_amdgcn_update_dpp(0, v, 0x141, 0xF, 0xF, true));
    v = __builtin_bit_cast(int, x);
    x += __builtin_bit_cast(float, __builtin_amdgcn_update_dpp(0, v, 0x140, 0xF, 0xF, true));
    return x;
}

// ---------------------------------------------------------------------------
// Kernel 0: W [E,D] f32 -> Wt2, the exact per-K-step LDS image (r16).
// ---------------------------------------------------------------------------
__global__ __launch_bounds__(256) void wt_kernel(const float* __restrict__ Wq,
                                                 const float* __restrict__ Wk,
                                                 const float* __restrict__ Wv,
                                                 u16* __restrict__ Wt) {
    int sid = blockIdx.x * 256 + threadIdx.x;   // 0 .. 49151 (16B slots)
    int l = sid & 63;
    int t8 = (sid >> 6) & 7;
    int ks = (sid >> 9) & 31;
    int w = sid >> 14;
    int g = l >> 4;
    int c = l & 15;
    int d = t8 * 16 + c;
    const float* W = (w == 0) ? Wq : ((w == 1) ? Wk : Wv);
    union { u16x8 v; u16 e[8]; } pk;
#pragma unroll
    for (int jj = 0; jj < 8; jj++) {
        int e = ks * 32 + g * 8 + jj;
        float v = W[(size_t)e * D_ + d];
        if (w == 0) v *= 0.08838834764831845f;   // 1/sqrt(128)
        pk.e[jj] = f2bf(v);
    }
    *(u16x8*)((char*)Wt + (size_t)sid * 16) = pk.v;
}

// ---------------------------------------------------------------------------
// Kernel 1: QKV LDS-staged GEMM, counted-vmcnt schedule (unchanged r16).
// ---------------------------------------------------------------------------
__global__ __launch_bounds__(512, 2) void qkv_fused(const float* __restrict__ x,
                                                    const u16* __restrict__ Wt,
                                                    u16* __restrict__ q,
                                                    u16* __restrict__ k,
                                                    u16* __restrict__ vT) {
    const int mrow0 = blockIdx.x * 64;
    const int wv = threadIdx.x >> 6;   // 0..7
    const int l = threadIdx.x & 63;
    const int g = l >> 4;
    const int c = l & 15;
    const int wr = wv >> 2;            // 0..1 (32-row half)
    const int wc = wv & 3;             // 0..3 (96-col group)

    __shared__ __align__(16) char wlds[2][24 * 1024];   // 48 KB dbuf W-tile

    auto STAGE_W = [&](int buf, int ksIdx) {
#pragma unroll
        for (int ii = 0; ii < 3; ii++) {
            int ct = wv * 3 + ii;                  // 0..23 ; w=ct>>3, t8=ct&7
            const char* gp = (const char*)Wt
                + ((size_t)(((ct >> 3) * 32 + ksIdx) * 8 + (ct & 7)) * 1024) + l * 16;
            gload16(gp, wlds[buf] + ct * 1024);
        }
    };

    const float* xrow[2];
#pragma unroll
    for (int sub = 0; sub < 2; sub++)
        xrow[sub] = x + (size_t)(mrow0 + wr * 32 + sub * 16 + c) * E_ + g * 8;

    f32x4 acc[2][6] = {};

    auto MF = [&](int buf, bf16x8 av0, bf16x8 av1) {
#pragma unroll
        for (int ct = 0; ct < 6; ct++) {
            u16x8 braw = *(const u16x8*)(wlds[buf] + (wc * 6 + ct) * 1024 + l * 16);
            bf16x8 bw = __builtin_bit_cast(bf16x8, braw);
            acc[0][ct] = __builtin_amdgcn_mfma_f32_16x16x32_bf16(av0, bw, acc[0][ct], 0, 0, 0);
            acc[1][ct] = __builtin_amdgcn_mfma_f32_16x16x32_bf16(av1, bw, acc[1][ct], 0, 0, 0);
        }
    };

    STAGE_W(0, 0);
    __builtin_amdgcn_sched_barrier(0);
    float4 xa00 = *(const float4*)(xrow[0]);
    float4 xa01 = *(const float4*)(xrow[0] + 4);
    float4 xa10 = *(const float4*)(xrow[1]);
    float4 xa11 = *(const float4*)(xrow[1] + 4);
    float4 xb00 = *(const float4*)(xrow[0] + 32);
    float4 xb01 = *(const float4*)(xrow[0] + 36);
    float4 xb10 = *(const float4*)(xrow[1] + 32);
    float4 xb11 = *(const float4*)(xrow[1] + 36);
    asm volatile("s_waitcnt vmcnt(8)" ::: "memory");
    __builtin_amdgcn_s_barrier();

    int buf = 0;
    for (int it = 0; it < 16; it++) {
        STAGE_W(buf ^ 1, 2 * it + 1);
        __builtin_amdgcn_sched_barrier(0);
        {
            bf16x8 av0 = cvt8(xa00, xa01);
            bf16x8 av1 = cvt8(xa10, xa11);
            if (it < 15) {
                xa00 = *(const float4*)(xrow[0] + (2 * it + 2) * 32);
                xa01 = *(const float4*)(xrow[0] + (2 * it + 2) * 32 + 4);
                xa10 = *(const float4*)(xrow[1] + (2 * it + 2) * 32);
                xa11 = *(const float4*)(xrow[1] + (2 * it + 2) * 32 + 4);
            }
            MF(buf, av0, av1);
        }
        if (it < 15) asm volatile("s_waitcnt vmcnt(4) lgkmcnt(0)" ::: "memory");
        else         asm volatile("s_waitcnt vmcnt(0) lgkmcnt(0)" ::: "memory");
        __builtin_amdgcn_s_barrier();
        buf ^= 1;

        if (it < 15) STAGE_W(buf ^ 1, 2 * it + 2);
        __builtin_amdgcn_sched_barrier(0);
        {
            bf16x8 av0 = cvt8(xb00, xb01);
            bf16x8 av1 = cvt8(xb10, xb11);
            if (it < 15) {
                xb00 = *(const float4*)(xrow[0] + (2 * it + 3) * 32);
                xb01 = *(const float4*)(xrow[0] + (2 * it + 3) * 32 + 4);
                xb10 = *(const float4*)(xrow[1] + (2 * it + 3) * 32);
                xb11 = *(const float4*)(xrow[1] + (2 * it + 3) * 32 + 4);
            }
            MF(buf, av0, av1);
        }
        if (it < 15) {
            asm volatile("s_waitcnt vmcnt(4) lgkmcnt(0)" ::: "memory");
            __builtin_amdgcn_s_barrier();
            buf ^= 1;
        }
    }

#pragma unroll
    for (int sub = 0; sub < 2; sub++) {
#pragma unroll
        for (int ct = 0; ct < 6; ct++) {
            int gc = (wc * 6 + ct) * 16;
            int proj = gc >> 7;
            int dcol = gc & 127;
            if (proj < 2) {
                u16* dst = proj ? k : q;
#pragma unroll
                for (int j = 0; j < 4; j++) {
                    int row = mrow0 + wr * 32 + sub * 16 + g * 4 + j;
                    dst[(size_t)row * D_ + dcol + c] = f2bf(acc[sub][ct][j]);
                }
            } else {
                int srow = mrow0 + wr * 32 + sub * 16 + g * 4;
                int b = srow >> 12;
                int s = srow & 4095;
                ushort4 pk;
                pk.x = f2bf(acc[sub][ct][0]);
                pk.y = f2bf(acc[sub][ct][1]);
                pk.z = f2bf(acc[sub][ct][2]);
                pk.w = f2bf(acc[sub][ct][3]);
                *(ushort4*)(vT + ((size_t)(b * D_ + dcol + c)) * S_ + s) = pk;
            }
        }
    }
}

// ---------------------------------------------------------------------------
// Kernel 2: flash attention, 1024 threads = 16 waves = 4 q-subs x 4 KV
// groups -> 4 waves/SIMD (r14 had 2; the serial chain is the wall).
// KVBLK=64 kept (r17: KVBLK=32 doubled DPP overhead). K staged (r14 exact
// layout, dbuf, 4 grp x 2 x 16KB = 128KB); V read DIRECT from L2
// (2MB/batch L2-resident; coalesced 4 lanes/64B line) - no V staging, so
// LDS fits and the barrier drain halves. One __syncthreads per round
// (16 rounds); its drain retires exactly the K-stage needed next round.
// Softmax/P r14-verbatim; merge r17's proven 4-way (overlay post-loop).
// ---------------------------------------------------------------------------
__global__ __launch_bounds__(1024, 4) void attn_kernel(const u16* __restrict__ q,
                                                       const u16* __restrict__ k,
                                                       const u16* __restrict__ vT,
                                                       float* __restrict__ out) {
    // bijective XCD-chunk swizzle (nwg=256, 8 XCDs, chunk=32)
    int bid = blockIdx.x;
    int sw = (bid & 7) * 32 + (bid >> 3);
    const int b = sw >> 6;          // batch 0..3 (2 XCDs per batch)
    const int qt = sw & 63;         // q-tile 0..63 (64 rows)
    const int wv = threadIdx.x >> 6;    // 0..15
    const int wq = wv >> 2;             // q-subtile 0..3 (16 rows)
    const int grp = wv & 3;             // kv group: kv [grp*1024, +1024)
    const int l = threadIdx.x & 63;
    const int g = l >> 4;
    const int c = l & 15;
    const int qrow0 = qt * 64 + wq * 16;   // within batch

    __shared__ __align__(16) char smem[163840];  // 128KB K bufs + 32KB plds
    char* kgrp = smem + grp * 32768;             // this group's 2 K bufs
    u16* pw = (u16*)(smem + 131072 + wv * 2048); // per-wave [16][128B] P

    const char* kbb = (const char*)(k + (size_t)b * S_ * D_);
    const char* vbb = (const char*)(vT + (size_t)b * D_ * S_);

    // Q fragments, hoisted (scaled already, via Wq)
    bf16x8 aq[4];
    const u16* qp = q + ((size_t)(b * S_ + qrow0 + c)) * D_ + g * 8;
#pragma unroll
    for (int ks = 0; ks < 4; ks++) aq[ks] = *(const bf16x8*)(qp + ks * 32);

    f32x4 o[8] = {};
    float m[4], ll[4];
#pragma unroll
    for (int j = 0; j < 4; j++) { m[j] = -1e30f; ll[j] = 0.0f; }

    // stage one 64-kv K tile (16KB) for this group; 4 instrs per wave
    // (the group's 4 wq-waves cover i = 0..15). r14 K layout: [64][256B]
    // rows, XOR (row&7)<<4 applied on the global source column.
    auto STAGE_K = [&](int buf, int kvbase) {
        char* dst = kgrp + buf * 16384;
#pragma unroll
        for (int ii = 0; ii < 4; ii++) {
            int i = wq * 4 + ii;                   // 0..15, 1KB each
            int row = i * 4 + (l >> 4);
            int colb = (l & 15) * 16;
            const char* gp = kbb + (size_t)(kvbase + row) * 256
                           + (colb ^ ((row & 7) << 4));
            gload16(gp, dst + i * 1024);
        }
    };

    STAGE_K(0, grp * 1024);
    __syncthreads();                 // drains vmcnt: buf0 ready
    const int swzK = (c & 7) << 4;

    int buf = 0;
    for (int t = 0; t < 16; t++) {
        const int kvbase = grp * 1024 + t * 64;
        if (t < 15) STAGE_K(buf ^ 1, kvbase + 64);

        const char* kbuf = kgrp + buf * 16384;

        // ---- S = Q K^T : 4 tiles of 16 kv-cols, K-dim 128 (r14) ----
        f32x4 s[4] = {};
        __builtin_amdgcn_s_setprio(1);
#pragma unroll
        for (int tt = 0; tt < 4; tt++) {
            int rb = (tt * 16 + c) * 256;
#pragma unroll
            for (int ks = 0; ks < 4; ks++) {
                u16x8 kr = *(const u16x8*)(kbuf + rb + ((ks * 64 + g * 16) ^ swzK));
                bf16x8 bk = __builtin_bit_cast(bf16x8, kr);
                s[tt] = __builtin_amdgcn_mfma_f32_16x16x32_bf16(aq[ks], bk, s[tt], 0, 0, 0);
            }
        }
        __builtin_amdgcn_s_setprio(0);

        // ---- online softmax: DPP reduce + defer-max (THR=8) (r14) ----
        float tmj[4];
        bool need = false;
#pragma unroll
        for (int j = 0; j < 4; j++) {
            float tm = fmaxf(fmaxf(s[0][j], s[1][j]), fmaxf(s[2][j], s[3][j]));
            tm = dpp_max16(tm);
            tmj[j] = tm;
            need = need || (tm > m[j] + 8.0f);
        }
        if (__any(need)) {
#pragma unroll
            for (int j = 0; j < 4; j++) {
                float mn = fmaxf(m[j], tmj[j]);
                float alpha = exp2f((m[j] - mn) * 1.44269504f);
                ll[j] *= alpha;
#pragma unroll
                for (int ct = 0; ct < 8; ct++) o[ct][j] *= alpha;
                m[j] = mn;
            }
        }
        float pv[4][4];
#pragma unroll
        for (int j = 0; j < 4; j++) {
            float rs = 0.f;
#pragma unroll
            for (int tt = 0; tt < 4; tt++) {
                float p = exp2f((s[tt][j] - m[j]) * 1.44269504f);
                pv[tt][j] = p;
                rs += p;
            }
            ll[j] += dpp_add16(rs);
        }

        // ---- P -> LDS (wave-private), XOR-swizzled (r14) ----
#pragma unroll
        for (int tt = 0; tt < 4; tt++) {
#pragma unroll
            for (int j = 0; j < 4; j++) {
                int r = g * 4 + j;
                int cf = tt * 16 + c;
                int slot = (cf >> 3) ^ ((r & 7) ^ ((r & 8) >> 2));
                pw[r * 64 + slot * 8 + (cf & 7)] = f2bf(pv[tt][j]);
            }
        }

        // ---- PV: O += P[16,64] * V[64,128]; V DIRECT from L2 ----
        __builtin_amdgcn_s_setprio(1);
#pragma unroll
        for (int st = 0; st < 2; st++) {
            int rho = c;
            int sigma = g + st * 4;
            int slot = sigma ^ ((rho & 7) ^ ((rho & 8) >> 2));
            u16x8 praw = *(const u16x8*)(pw + rho * 64 + slot * 8);
            bf16x8 pa = __builtin_bit_cast(bf16x8, praw);
#pragma unroll
            for (int ct = 0; ct < 8; ct++) {
                const char* vp = vbb + (size_t)(ct * 16 + c) * 8192
                               + (size_t)(kvbase + st * 32 + g * 8) * 2;
                bf16x8 bv = __builtin_bit_cast(bf16x8, *(const u16x8*)vp);
                o[ct] = __builtin_amdgcn_mfma_f32_16x16x32_bf16(pa, bv, o[ct], 0, 0, 0);
            }
        }
        __builtin_amdgcn_s_setprio(0);

        __syncthreads();    // drain K-stage (consumed next round) + barrier
        buf ^= 1;
    }

    // ---- 4-way merge: grps 1..3 -> LDS overlay, grp 0 merges and stores ----
    float* co = (float*)smem;                       // 96KB overlay on K bufs
    float* cmB = (float*)(smem + 131072);           // overlay on plds (wv0 = grp0)
    float* clB = cmB + 256;
    if (grp != 0) {
        float* cg = co + (size_t)(grp - 1) * (64 * 128);
#pragma unroll
        for (int ct = 0; ct < 8; ct++) {
#pragma unroll
            for (int j = 0; j < 4; j++) {
                int r = wq * 16 + g * 4 + j;
                cg[(size_t)r * 128 + ct * 16 + c] = o[ct][j];
            }
        }
        if (c == 0) {
#pragma unroll
            for (int j = 0; j < 4; j++) {
                int r = wq * 16 + g * 4 + j;
                cmB[grp * 64 + r] = m[j];
                clB[grp * 64 + r] = ll[j];
            }
        }
    }
    __syncthreads();
    if (grp == 0) {
#pragma unroll
        for (int j = 0; j < 4; j++) {
            int r = wq * 16 + g * 4 + j;
            float M = m[j];
#pragma unroll
            for (int gi = 1; gi < 4; gi++) M = fmaxf(M, cmB[gi * 64 + r]);
            float e0 = exp2f((m[j] - M) * 1.44269504f);
            float L = ll[j] * e0;
            float eg[3];
#pragma unroll
            for (int gi = 1; gi < 4; gi++) {
                eg[gi - 1] = exp2f((cmB[gi * 64 + r] - M) * 1.44269504f);
                L += clB[gi * 64 + r] * eg[gi - 1];
            }
            float rL = 1.0f / L;
            float* op = out + ((size_t)(b * S_ + qt * 64 + r)) * D_;
#pragma unroll
            for (int ct = 0; ct < 8; ct++) {
                float a = o[ct][j] * e0;
#pragma unroll
                for (int gi = 1; gi < 4; gi++)
                    a += co[(size_t)(gi - 1) * (64 * 128) + (size_t)r * 128 + ct * 16 + c] * eg[gi - 1];
                op[ct * 16 + c] = a * rL;
            }
        }
    }
}

extern "C" void kernel_launch(void* const* d_in, const int* in_sizes, int n_in,
                              void* d_out, int out_size, void* d_ws, size_t ws_size,
                              hipStream_t stream) {
    const float* x  = (const float*)d_in[0];
    const float* Wq = (const float*)d_in[1];
    const float* Wk = (const float*)d_in[2];
    const float* Wv = (const float*)d_in[3];
    float* out = (float*)d_out;   // reference output dtype is float32

    // workspace layout (bytes): q 4MB | k 4MB | vT 4MB | Wt2 768KB
    u16* q  = (u16*)d_ws;
    u16* k  = q  + (size_t)B_ * S_ * D_;
    u16* vT = k  + (size_t)B_ * S_ * D_;
    u16* Wt = vT + (size_t)B_ * S_ * D_;

    wt_kernel<<<(3 * 32 * 8 * 64) / 256, 256, 0, stream>>>(Wq, Wk, Wv, Wt);
    qkv_fused<<<(B_ * S_) / 64, 512, 0, stream>>>(x, Wt, q, k, vT);
    attn_kernel<<<(B_ * S_) / 64, 1024, 0, stream>>>(q, k, vT, out);
}

// Round 19
// 138.849 us; speedup vs baseline: 1.5218x; 1.5218x over previous
//
#include <hip/hip_runtime.h>
#include <hip/hip_bf16.h>

#define B_ 4
#define S_ 4096
#define E_ 1024
#define D_ 128

typedef unsigned short u16;
typedef __bf16 bf16x8 __attribute__((ext_vector_type(8)));
typedef unsigned short u16x8 __attribute__((ext_vector_type(8)));
typedef float f32x4 __attribute__((ext_vector_type(4)));

__device__ inline u16 f2bf(float f) {
    __bf16 h = (__bf16)f;
    return __builtin_bit_cast(u16, h);
}

// direct global->LDS DMA, 16B per lane, no VGPR round-trip
__device__ inline void gload16(const void* g, void* l) {
    __builtin_amdgcn_global_load_lds(
        (const __attribute__((address_space(1))) void*)g,
        (__attribute__((address_space(3))) void*)l, 16, 0, 0);
}

__device__ inline bf16x8 cvt8(float4 lo, float4 hi) {
    union { bf16x8 v; __bf16 e[8]; } a;
    a.e[0] = (__bf16)lo.x; a.e[1] = (__bf16)lo.y;
    a.e[2] = (__bf16)lo.z; a.e[3] = (__bf16)lo.w;
    a.e[4] = (__bf16)hi.x; a.e[5] = (__bf16)hi.y;
    a.e[6] = (__bf16)hi.z; a.e[7] = (__bf16)hi.w;
    return a.v;
}

// VALU-pipe (DPP) butterfly reductions over 16-lane rows.
__device__ inline float dpp_max16(float x) {
    int v = __builtin_bit_cast(int, x);
    x = fmaxf(x, __builtin_bit_cast(float, __builtin_amdgcn_update_dpp(0, v, 0xB1, 0xF, 0xF, true)));
    v = __builtin_bit_cast(int, x);
    x = fmaxf(x, __builtin_bit_cast(float, __builtin_amdgcn_update_dpp(0, v, 0x4E, 0xF, 0xF, true)));
    v = __builtin_bit_cast(int, x);
    x = fmaxf(x, __builtin_bit_cast(float, __builtin_amdgcn_update_dpp(0, v, 0x141, 0xF, 0xF, true)));
    v = __builtin_bit_cast(int, x);
    x = fmaxf(x, __builtin_bit_cast(float, __builtin_amdgcn_update_dpp(0, v, 0x140, 0xF, 0xF, true)));
    return x;
}
__device__ inline float dpp_add16(float x) {
    int v = __builtin_bit_cast(int, x);
    x += __builtin_bit_cast(float, __builtin_amdgcn_update_dpp(0, v, 0xB1, 0xF, 0xF, true));
    v = __builtin_bit_cast(int, x);
    x += __builtin_bit_cast(float, __builtin_amdgcn_update_dpp(0, v, 0x4E, 0xF, 0xF, true));
    v = __builtin_bit_cast(int, x);
    x += __builtin_bit_cast(float, __builtin_amdgcn_update_dpp(0, v, 0x141, 0xF, 0xF, true));
    v = __builtin_bit_cast(int, x);
    x += __builtin_bit_cast(float, __builtin_amdgcn_update_dpp(0, v, 0x140, 0xF, 0xF, true));
    return x;
}

// ---------------------------------------------------------------------------
// Kernel 0: W [E,D] f32 -> Wt2, the exact per-K-step LDS image (r16).
// ---------------------------------------------------------------------------
__global__ __launch_bounds__(256) void wt_kernel(const float* __restrict__ Wq,
                                                 const float* __restrict__ Wk,
                                                 const float* __restrict__ Wv,
                                                 u16* __restrict__ Wt) {
    int sid = blockIdx.x * 256 + threadIdx.x;   // 0 .. 49151 (16B slots)
    int l = sid & 63;
    int t8 = (sid >> 6) & 7;
    int ks = (sid >> 9) & 31;
    int w = sid >> 14;
    int g = l >> 4;
    int c = l & 15;
    int d = t8 * 16 + c;
    const float* W = (w == 0) ? Wq : ((w == 1) ? Wk : Wv);
    union { u16x8 v; u16 e[8]; } pk;
#pragma unroll
    for (int jj = 0; jj < 8; jj++) {
        int e = ks * 32 + g * 8 + jj;
        float v = W[(size_t)e * D_ + d];
        if (w == 0) v *= 0.08838834764831845f;   // 1/sqrt(128)
        pk.e[jj] = f2bf(v);
    }
    *(u16x8*)((char*)Wt + (size_t)sid * 16) = pk.v;
}

// ---------------------------------------------------------------------------
// Kernel 1: QKV LDS-staged GEMM, BK=64 (2 k-steps per phase): 16 phases
// instead of r16's 31. Per phase: 6 W-stage gload_lds (96KB dbuf) + 8 x
// prefetch loads (2-phase ring, static names) + 24 MFMA; end with
// s_waitcnt vmcnt(8) + raw s_barrier (W complete, x spans the barrier).
// r16 tripwire: per-phase fixed cost (barrier + drain + reconvergence)
// dominated a ~300cyc issue phase; halving phase count amortizes it.
// ---------------------------------------------------------------------------
__global__ __launch_bounds__(512, 2) void qkv_fused(const float* __restrict__ x,
                                                    const u16* __restrict__ Wt,
                                                    u16* __restrict__ q,
                                                    u16* __restrict__ k,
                                                    u16* __restrict__ vT) {
    const int mrow0 = blockIdx.x * 64;
    const int wv = threadIdx.x >> 6;   // 0..7
    const int l = threadIdx.x & 63;
    const int g = l >> 4;
    const int c = l & 15;
    const int wr = wv >> 2;            // 0..1 (32-row half)
    const int wc = wv & 3;             // 0..3 (96-col group)

    __shared__ __align__(16) char wlds[2][48 * 1024];   // 96 KB dbuf (2 k-steps)

    // stage both k-steps (2*ph, 2*ph+1) of phase ph into buf: 6 x 1KB reads
    auto STAGE_W2 = [&](int buf, int ph) {
#pragma unroll
        for (int half = 0; half < 2; half++) {
            int ksIdx = ph * 2 + half;
#pragma unroll
            for (int ii = 0; ii < 3; ii++) {
                int ct = wv * 3 + ii;              // 0..23 ; w=ct>>3, t8=ct&7
                const char* gp = (const char*)Wt
                    + ((size_t)(((ct >> 3) * 32 + ksIdx) * 8 + (ct & 7)) * 1024) + l * 16;
                gload16(gp, wlds[buf] + half * 24576 + ct * 1024);
            }
        }
    };

    const float* xrow[2];
#pragma unroll
    for (int sub = 0; sub < 2; sub++)
        xrow[sub] = x + (size_t)(mrow0 + wr * 32 + sub * 16 + c) * E_ + g * 8;

    f32x4 acc[2][6] = {};

    auto MF2 = [&](int bufv, int half, bf16x8 av0, bf16x8 av1) {
#pragma unroll
        for (int ct = 0; ct < 6; ct++) {
            u16x8 braw = *(const u16x8*)(wlds[bufv] + half * 24576 + (wc * 6 + ct) * 1024 + l * 16);
            bf16x8 bw = __builtin_bit_cast(bf16x8, braw);
            acc[0][ct] = __builtin_amdgcn_mfma_f32_16x16x32_bf16(av0, bw, acc[0][ct], 0, 0, 0);
            acc[1][ct] = __builtin_amdgcn_mfma_f32_16x16x32_bf16(av1, bw, acc[1][ct], 0, 0, 0);
        }
    };

    // prologue: stage phase 0; x for phase 0 (slot A) and phase 1 (slot B)
    STAGE_W2(0, 0);
    __builtin_amdgcn_sched_barrier(0);
    float4 xa000 = *(const float4*)(xrow[0]);
    float4 xa001 = *(const float4*)(xrow[0] + 4);
    float4 xa010 = *(const float4*)(xrow[0] + 32);
    float4 xa011 = *(const float4*)(xrow[0] + 36);
    float4 xa100 = *(const float4*)(xrow[1]);
    float4 xa101 = *(const float4*)(xrow[1] + 4);
    float4 xa110 = *(const float4*)(xrow[1] + 32);
    float4 xa111 = *(const float4*)(xrow[1] + 36);
    float4 xb000 = *(const float4*)(xrow[0] + 64);
    float4 xb001 = *(const float4*)(xrow[0] + 68);
    float4 xb010 = *(const float4*)(xrow[0] + 96);
    float4 xb011 = *(const float4*)(xrow[0] + 100);
    float4 xb100 = *(const float4*)(xrow[1] + 64);
    float4 xb101 = *(const float4*)(xrow[1] + 68);
    float4 xb110 = *(const float4*)(xrow[1] + 96);
    float4 xb111 = *(const float4*)(xrow[1] + 100);
    asm volatile("s_waitcnt vmcnt(16)" ::: "memory");   // W(0) done; x in flight
    __builtin_amdgcn_s_barrier();

    int buf = 0;
    for (int it = 0; it < 8; it++) {
        // ---- even phase ph = 2*it (slot A) ----
        STAGE_W2(buf ^ 1, 2 * it + 1);
        __builtin_amdgcn_sched_barrier(0);
        {
            bf16x8 av00 = cvt8(xa000, xa001), av01 = cvt8(xa010, xa011);
            bf16x8 av10 = cvt8(xa100, xa101), av11 = cvt8(xa110, xa111);
            if (it < 7) {
                int f0 = (2 * it + 2) * 64;        // float offset of phase ph+2
                xa000 = *(const float4*)(xrow[0] + f0);
                xa001 = *(const float4*)(xrow[0] + f0 + 4);
                xa010 = *(const float4*)(xrow[0] + f0 + 32);
                xa011 = *(const float4*)(xrow[0] + f0 + 36);
                xa100 = *(const float4*)(xrow[1] + f0);
                xa101 = *(const float4*)(xrow[1] + f0 + 4);
                xa110 = *(const float4*)(xrow[1] + f0 + 32);
                xa111 = *(const float4*)(xrow[1] + f0 + 36);
            }
            MF2(buf, 0, av00, av10);
            MF2(buf, 1, av01, av11);
        }
        if (it < 7) asm volatile("s_waitcnt vmcnt(8) lgkmcnt(0)" ::: "memory");
        else        asm volatile("s_waitcnt vmcnt(0) lgkmcnt(0)" ::: "memory");
        __builtin_amdgcn_s_barrier();
        buf ^= 1;

        // ---- odd phase ph = 2*it+1 (slot B) ----
        if (it < 7) STAGE_W2(buf ^ 1, 2 * it + 2);
        __builtin_amdgcn_sched_barrier(0);
        {
            bf16x8 av00 = cvt8(xb000, xb001), av01 = cvt8(xb010, xb011);
            bf16x8 av10 = cvt8(xb100, xb101), av11 = cvt8(xb110, xb111);
            if (it < 7) {
                int f0 = (2 * it + 3) * 64;
                xb000 = *(const float4*)(xrow[0] + f0);
                xb001 = *(const float4*)(xrow[0] + f0 + 4);
                xb010 = *(const float4*)(xrow[0] + f0 + 32);
                xb011 = *(const float4*)(xrow[0] + f0 + 36);
                xb100 = *(const float4*)(xrow[1] + f0);
                xb101 = *(const float4*)(xrow[1] + f0 + 4);
                xb110 = *(const float4*)(xrow[1] + f0 + 32);
                xb111 = *(const float4*)(xrow[1] + f0 + 36);
            }
            MF2(buf, 0, av00, av10);
            MF2(buf, 1, av01, av11);
        }
        if (it < 7) {
            asm volatile("s_waitcnt vmcnt(8) lgkmcnt(0)" ::: "memory");
            __builtin_amdgcn_s_barrier();
            buf ^= 1;
        }
    }

    // ---- epilogue (registers only) ----
#pragma unroll
    for (int sub = 0; sub < 2; sub++) {
#pragma unroll
        for (int ct = 0; ct < 6; ct++) {
            int gc = (wc * 6 + ct) * 16;
            int proj = gc >> 7;
            int dcol = gc & 127;
            if (proj < 2) {
                u16* dst = proj ? k : q;
#pragma unroll
                for (int j = 0; j < 4; j++) {
                    int row = mrow0 + wr * 32 + sub * 16 + g * 4 + j;
                    dst[(size_t)row * D_ + dcol + c] = f2bf(acc[sub][ct][j]);
                }
            } else {
                int srow = mrow0 + wr * 32 + sub * 16 + g * 4;
                int b = srow >> 12;
                int s = srow & 4095;
                ushort4 pk;
                pk.x = f2bf(acc[sub][ct][0]);
                pk.y = f2bf(acc[sub][ct][1]);
                pk.z = f2bf(acc[sub][ct][2]);
                pk.w = f2bf(acc[sub][ct][3]);
                *(ushort4*)(vT + ((size_t)(b * D_ + dcol + c)) * S_ + s) = pk;
            }
        }
    }
}

// ---------------------------------------------------------------------------
// Kernel 2: flash attention — r14-EXACT (best measured: 97.1-97.4us).
// r17 (32q/wave, KVBLK=32) = 105.7; r18 (4 waves/SIMD, V-direct) = 166.5.
// The r14 schedule is a verified local optimum: KVBLK=64, even/odd 2-way
// split, dbuf K+V staged (XOR-swizzled 256B-contiguous source), one
// barrier/round, DPP softmax + defer-max + setprio.
// ---------------------------------------------------------------------------
__global__ __launch_bounds__(512) void attn_kernel(const u16* __restrict__ q,
                                                   const u16* __restrict__ k,
                                                   const u16* __restrict__ vT,
                                                   float* __restrict__ out) {
    // bijective XCD-chunk swizzle (nwg=256, 8 XCDs, chunk=32)
    int bid = blockIdx.x;
    int sw = (bid & 7) * 32 + (bid >> 3);
    const int b = sw >> 6;          // batch 0..3 (2 XCDs per batch)
    const int qt = sw & 63;         // q-tile 0..63 (64 rows)
    const int wv = threadIdx.x >> 6;    // 0..7
    const int grp = wv >> 2;            // 0 = even tiles, 1 = odd tiles
    const int wq = wv & 3;              // q-subtile within block
    const int l = threadIdx.x & 63;
    const int g = l >> 4;
    const int c = l & 15;
    const int qrow0 = qt * 64 + wq * 16;   // within batch

    __shared__ __align__(16) char kv_lds[4 * 32768];   // 4 bufs (K 16K | V 16K)
    __shared__ __align__(16) u16 plds[8][1024];        // per-wave 2KB P buffer
    __shared__ float cmB[64], clB[64];
    u16* pw = &plds[wv][0];

    const char* kbb = (const char*)(k + (size_t)b * S_ * D_);
    const char* vbb = (const char*)(vT + (size_t)b * D_ * S_);

    // Q fragments, hoisted (scaled already, via Wq)
    bf16x8 aq[4];
    const u16* qp = q + ((size_t)(b * S_ + qrow0 + c)) * D_ + g * 8;
#pragma unroll
    for (int ks = 0; ks < 4; ks++) aq[ks] = *(const bf16x8*)(qp + ks * 32);

    f32x4 o[8] = {};
    float m[4], ll[4];
#pragma unroll
    for (int j = 0; j < 4; j++) { m[j] = -1e30f; ll[j] = 0.0f; }

    auto STAGE = [&](int buf, int kvbase) {
#pragma unroll
        for (int ii = 0; ii < 4; ii++) {           // K: [64][256B] rows
            int i = wq * 4 + ii;                   // instr 0..15, 1KB each
            int row = i * 4 + (l >> 4);
            int colb = (l & 15) * 16;
            const char* gp = kbb + (size_t)kvbase * 256 + (size_t)row * 256
                           + (colb ^ ((row & 7) << 4));
            gload16(gp, kv_lds + buf * 32768 + i * 1024);
        }
#pragma unroll
        for (int ii = 0; ii < 4; ii++) {           // V: [128][128B] rows
            int i = wq * 4 + ii;
            int row = i * 8 + (l >> 3);
            int colb = (l & 7) * 16;
            const char* gp = vbb + (size_t)row * 8192 + (size_t)kvbase * 2
                           + (colb ^ ((row & 7) << 4));
            gload16(gp, kv_lds + buf * 32768 + 16384 + i * 1024);
        }
    };

    STAGE(grp, grp * 64);
    __syncthreads();                 // drains vmcnt: bufs 0,1 ready
    const int swz = (c & 7) << 4;

    for (int t = 0; t < 32; t++) {
        const int mytile = 2 * t + grp;
        if (t < 31) STAGE((mytile + 2) & 3, (mytile + 2) * 64);

        const char* kbuf = kv_lds + (mytile & 3) * 32768;
        const char* vbuf = kbuf + 16384;

        // ---- S = Q K^T : 4 tiles of 16 kv-cols, K-dim 128 ----
        f32x4 s[4] = {};
        __builtin_amdgcn_s_setprio(1);
#pragma unroll
        for (int tt = 0; tt < 4; tt++) {
            int rb = (tt * 16 + c) * 256;
#pragma unroll
            for (int ks = 0; ks < 4; ks++) {
                u16x8 kr = *(const u16x8*)(kbuf + rb + ((ks * 64 + g * 16) ^ swz));
                bf16x8 bk = __builtin_bit_cast(bf16x8, kr);
                s[tt] = __builtin_amdgcn_mfma_f32_16x16x32_bf16(aq[ks], bk, s[tt], 0, 0, 0);
            }
        }
        __builtin_amdgcn_s_setprio(0);

        // ---- online softmax: DPP reduce + defer-max (THR=8) ----
        float tmj[4];
        bool need = false;
#pragma unroll
        for (int j = 0; j < 4; j++) {
            float tm = fmaxf(fmaxf(s[0][j], s[1][j]), fmaxf(s[2][j], s[3][j]));
            tm = dpp_max16(tm);
            tmj[j] = tm;
            need = need || (tm > m[j] + 8.0f);
        }
        if (__any(need)) {
#pragma unroll
            for (int j = 0; j < 4; j++) {
                float mn = fmaxf(m[j], tmj[j]);
                float alpha = exp2f((m[j] - mn) * 1.44269504f);
                ll[j] *= alpha;
#pragma unroll
                for (int ct = 0; ct < 8; ct++) o[ct][j] *= alpha;
                m[j] = mn;
            }
        }
        float pv[4][4];
#pragma unroll
        for (int j = 0; j < 4; j++) {
            float rs = 0.f;
#pragma unroll
            for (int tt = 0; tt < 4; tt++) {
                float p = exp2f((s[tt][j] - m[j]) * 1.44269504f);
                pv[tt][j] = p;
                rs += p;
            }
            ll[j] += dpp_add16(rs);
        }

        // ---- P -> LDS (wave-private), XOR-swizzled ----
#pragma unroll
        for (int tt = 0; tt < 4; tt++) {
#pragma unroll
            for (int j = 0; j < 4; j++) {
                int r = g * 4 + j;
                int cf = tt * 16 + c;
                int slot = (cf >> 3) ^ ((r & 7) ^ ((r & 8) >> 2));
                pw[r * 64 + slot * 8 + (cf & 7)] = f2bf(pv[tt][j]);
            }
        }

        // ---- PV: O += P[16,64] * V[64,128] ----
        __builtin_amdgcn_s_setprio(1);
#pragma unroll
        for (int st = 0; st < 2; st++) {
            int rho = c;
            int sigma = g + st * 4;
            int slot = sigma ^ ((rho & 7) ^ ((rho & 8) >> 2));
            u16x8 praw = *(const u16x8*)(pw + rho * 64 + slot * 8);
            bf16x8 pa = __builtin_bit_cast(bf16x8, praw);
#pragma unroll
            for (int ct = 0; ct < 8; ct++) {
                int rb = (ct * 16 + c) * 128;
                u16x8 vr = *(const u16x8*)(vbuf + rb + ((st * 64 + g * 16) ^ swz));
                bf16x8 bv = __builtin_bit_cast(bf16x8, vr);
                o[ct] = __builtin_amdgcn_mfma_f32_16x16x32_bf16(pa, bv, o[ct], 0, 0, 0);
            }
        }
        __builtin_amdgcn_s_setprio(0);

        __syncthreads();    // drain staging vmcnt + round barrier
    }

    // ---- 2-way merge: grp 1 -> LDS, grp 0 merges and stores ----
    float* co = (float*)kv_lds;     // 32KB, staging complete
    if (grp == 1) {
#pragma unroll
        for (int ct = 0; ct < 8; ct++) {
#pragma unroll
            for (int j = 0; j < 4; j++)
                co[(size_t)(wq * 16 + g * 4 + j) * 128 + ct * 16 + c] = o[ct][j];
        }
        if (c == 0) {
#pragma unroll
            for (int j = 0; j < 4; j++) {
                cmB[wq * 16 + g * 4 + j] = m[j];
                clB[wq * 16 + g * 4 + j] = ll[j];
            }
        }
    }
    __syncthreads();
    if (grp == 0) {
#pragma unroll
        for (int j = 0; j < 4; j++) {
            int r = wq * 16 + g * 4 + j;
            float mB = cmB[r], lB = clB[r];
            float M = fmaxf(m[j], mB);
            float eA = exp2f((m[j] - M) * 1.44269504f);
            float eB = exp2f((mB - M) * 1.44269504f);
            float rL = 1.0f / (ll[j] * eA + lB * eB);
            float* op = out + ((size_t)(b * S_ + qt * 64 + r)) * D_;
#pragma unroll
            for (int ct = 0; ct < 8; ct++) {
                op[ct * 16 + c] = (o[ct][j] * eA + co[(size_t)r * 128 + ct * 16 + c] * eB) * rL;
            }
        }
    }
}

extern "C" void kernel_launch(void* const* d_in, const int* in_sizes, int n_in,
                              void* d_out, int out_size, void* d_ws, size_t ws_size,
                              hipStream_t stream) {
    const float* x  = (const float*)d_in[0];
    const float* Wq = (const float*)d_in[1];
    const float* Wk = (const float*)d_in[2];
    const float* Wv = (const float*)d_in[3];
    float* out = (float*)d_out;   // reference output dtype is float32

    // workspace layout (bytes): q 4MB | k 4MB | vT 4MB | Wt2 768KB
    u16* q  = (u16*)d_ws;
    u16* k  = q  + (size_t)B_ * S_ * D_;
    u16* vT = k  + (size_t)B_ * S_ * D_;
    u16* Wt = vT + (size_t)B_ * S_ * D_;

    wt_kernel<<<(3 * 32 * 8 * 64) / 256, 256, 0, stream>>>(Wq, Wk, Wv, Wt);
    qkv_fused<<<(B_ * S_) / 64, 512, 0, stream>>>(x, Wt, q, k, vT);
    attn_kernel<<<(B_ * S_) / 64, 512, 0, stream>>>(q, k, vT, out);
}